// Round 1
// baseline (2298.546 us; speedup 1.0000x reference)
//
#include <hip/hip_runtime.h>
#include <math.h>

#define B_ 32
#define T_ 128
#define H_ 300
#define HG 1200   // 4*H

__device__ __forceinline__ float sigm(float x){ return 1.f/(1.f+expf(-x)); }

// ---------------- embedding gather ----------------
__global__ __launch_bounds__(256) void k_embed(const int* __restrict__ prem, const int* __restrict__ hyp,
    const float* __restrict__ emb, float* __restrict__ X)
{
  int i = blockIdx.x*256 + threadIdx.x;     // over 2*B*T*75 float4s
  const int TOT = 2*B_*T_*75;
  if (i >= TOT) return;
  int f4 = i % 75;
  int bt = i / 75;          // 0..8191
  int side = bt >> 12;      // /4096
  int bt2 = bt & 4095;
  int tok = (side==0 ? prem : hyp)[bt2];
  float4 v = ((const float4*)(emb + (size_t)tok*H_))[f4];
  ((float4*)(X + (size_t)bt*H_))[f4] = v;
}

// ---------------- weight prep: uh[1] transpose ----------------
__global__ __launch_bounds__(256) void k_prep_uh1T(const float* __restrict__ enc_uh, const float* __restrict__ comp_uh,
    float* __restrict__ te, float* __restrict__ tc)
{
  int i = blockIdx.x*256 + threadIdx.x;
  if (i >= H_*H_) return;
  int m = i / H_, k = i % H_;
  te[i] = enc_uh[H_*H_ + (size_t)k*H_ + m];   // te[m][k] = uh1[k][m]
  tc[i] = comp_uh[H_*H_ + (size_t)k*H_ + m];
}

// ---------------- has_parent flags ----------------
__global__ void k_hasp(const float* __restrict__ lg, const float* __restrict__ rg, int* __restrict__ hasp)
{
  int chain = blockIdx.x; int s = chain >> 5, b = chain & 31;
  const float* g = (s ? rg : lg) + (size_t)b*T_*T_;
  int t = threadIdx.x;
  int any = 0;
  for (int j = t+1; j < T_; ++j) if (g[(size_t)j*T_ + t] != 0.f) { any = 1; break; }
  hasp[chain*T_ + t] = any;
}

// ---------------- generic fp32 GEMM: C[M,N] = act(A[M,K] @ W[N,K]^T + bias[N]) ----------------
#define BKT 16
__global__ __launch_bounds__(256) void k_gemm_nt(const float* __restrict__ A, const float* __restrict__ W,
    const float* __restrict__ bias, float* __restrict__ C, int M, int N, int K, int act)
{
  __shared__ float As[BKT][132];
  __shared__ float Ws[BKT][132];
  int bn = blockIdx.x * 128;
  int bm = blockIdx.y * 128;
  int tid = threadIdx.x;
  int tx = tid & 15, ty = tid >> 4;
  float acc[8][8];
  #pragma unroll
  for (int i = 0; i < 8; ++i)
    #pragma unroll
    for (int j = 0; j < 8; ++j) acc[i][j] = 0.f;

  for (int k0 = 0; k0 < K; k0 += BKT) {
    int kk = (tid & 3) * 4;
    int row = tid >> 2;       // 0..63
    #pragma unroll
    for (int r = 0; r < 2; ++r) {
      int m = row + r*64;
      int gk = k0 + kk;
      float4 v = make_float4(0.f,0.f,0.f,0.f);
      if (bm + m < M) {
        const float* ap = A + (size_t)(bm+m)*K + gk;
        if (gk + 3 < K) v = *(const float4*)ap;
        else { if (gk<K) v.x=ap[0]; if (gk+1<K) v.y=ap[1]; if (gk+2<K) v.z=ap[2]; if (gk+3<K) v.w=ap[3]; }
      }
      As[kk+0][m]=v.x; As[kk+1][m]=v.y; As[kk+2][m]=v.z; As[kk+3][m]=v.w;
      int n = row + r*64;
      float4 w = make_float4(0.f,0.f,0.f,0.f);
      if (bn + n < N) {
        const float* wp = W + (size_t)(bn+n)*K + gk;
        if (gk + 3 < K) w = *(const float4*)wp;
        else { if (gk<K) w.x=wp[0]; if (gk+1<K) w.y=wp[1]; if (gk+2<K) w.z=wp[2]; if (gk+3<K) w.w=wp[3]; }
      }
      Ws[kk+0][n]=w.x; Ws[kk+1][n]=w.y; Ws[kk+2][n]=w.z; Ws[kk+3][n]=w.w;
    }
    __syncthreads();
    #pragma unroll
    for (int kk2 = 0; kk2 < BKT; ++kk2) {
      float a[8], b[8];
      *(float4*)&a[0] = *(const float4*)&As[kk2][ty*8];
      *(float4*)&a[4] = *(const float4*)&As[kk2][ty*8+4];
      *(float4*)&b[0] = *(const float4*)&Ws[kk2][tx*8];
      *(float4*)&b[4] = *(const float4*)&Ws[kk2][tx*8+4];
      #pragma unroll
      for (int i = 0; i < 8; ++i)
        #pragma unroll
        for (int j = 0; j < 8; ++j) acc[i][j] = fmaf(a[i], b[j], acc[i][j]);
    }
    __syncthreads();
  }
  #pragma unroll
  for (int i = 0; i < 8; ++i) {
    int m = bm + ty*8 + i;
    if (m >= M) continue;
    #pragma unroll
    for (int j = 0; j < 8; ++j) {
      int n = bn + tx*8 + j;
      if (n >= N) continue;
      float v = acc[i][j] + bias[n];
      if (act == 1) v = fmaxf(v, 0.f);
      C[(size_t)m*N + n] = v;
    }
  }
}

// ---------------- tree-LSTM scan: one block per (side,batch) chain ----------------
__global__ __launch_bounds__(320) void k_tree_scan(
    const float* __restrict__ xg,   // (2,B,T,1200)
    const float* __restrict__ bhv,  // (4,300)
    const float* __restrict__ uh1T, // (300,300) [m][k]
    const float* __restrict__ lg, const float* __restrict__ rg,
    const int* __restrict__ hasp,   // (64,128)
    float* __restrict__ hout, float* __restrict__ chist, float* __restrict__ fh)
{
  int chain = blockIdx.x; int s = chain >> 5, b = chain & 31;
  const float* graph = (s ? rg : lg) + (size_t)b*T_*T_;
  int tid = threadIdx.x;
  bool act = tid < H_;
  float bh0=0.f,bh1=0.f,bh2=0.f,bh3=0.f;
  if (act) { bh0=bhv[tid]; bh1=bhv[H_+tid]; bh2=bhv[2*H_+tid]; bh3=bhv[3*H_+tid]; }
  __shared__ float h_lds[H_];
  __shared__ int nchild;
  __shared__ int   cidx[T_];
  __shared__ float cwt[T_];
  size_t cb = (size_t)chain * T_ * H_;
  size_t xb = (size_t)chain * T_ * HG;

  for (int j = 0; j < T_; ++j) {
    if (tid == 0) nchild = 0;
    __syncthreads();
    if (tid < j) {                       // strictly earlier positions only
      float g = graph[(size_t)j*T_ + tid];
      if (g != 0.f) { int p = atomicAdd(&nchild, 1); cidx[p] = tid; cwt[p] = g; }
    }
    float x1b = 0.f, iu = 0.f, og = 0.f;
    if (act) {
      const float* xp = xg + xb + (size_t)j*HG;
      float x0 = xp[tid], x1 = xp[H_+tid], x2 = xp[2*H_+tid], x3 = xp[3*H_+tid];
      iu  = sigm(x0+bh0) * tanhf(x3+bh3);
      og  = sigm(x2+bh2);
      x1b = x1 + bh1;
    }
    __syncthreads();
    int nc = nchild;
    float acc = iu;
    for (int e = 0; e < nc; ++e) {
      int t = cidx[e]; float w = cwt[e];
      if (act) {
        float fv = fh[cb + (size_t)t*H_ + tid];
        float cv = chist[cb + (size_t)t*H_ + tid];
        acc += w * sigm(x1b + fv) * cv;
      }
    }
    if (act) {
      chist[cb + (size_t)j*H_ + tid] = acc;
      float hv = og * tanhf(acc);
      hout[cb + (size_t)j*H_ + tid] = hv;
      h_lds[tid] = hv;
    }
    __syncthreads();
    if (hasp[chain*T_ + j] && act) {     // matvec only if some later node consumes it
      float a = 0.f;
      const float* up = uh1T + tid;
      #pragma unroll 4
      for (int m = 0; m < H_; ++m) a = fmaf(up[m*H_], h_lds[m], a);
      fh[cb + (size_t)j*H_ + tid] = a;
    }
    __syncthreads();
  }
}

// ---------------- fused attention (one direction per blockIdx.x) ----------------
#define NEGV -10000000.0f
__global__ __launch_bounds__(256) void k_attention(const float* __restrict__ H,  // (2,B,T,300)
    const int* __restrict__ plen, const int* __restrict__ hlen, float* __restrict__ ATT)
{
  int d = blockIdx.x;          // 0: q=enc_p,k=enc_h,mask=hlen ; 1: q=enc_h,k=enc_p,mask=plen
  int b = blockIdx.y;
  int r0 = blockIdx.z * 8;
  int qs = d, ks = 1 - d;
  int klen = (d == 0 ? hlen[b] : plen[b]);
  const float* Q  = H + ((size_t)(qs*B_ + b)*T_) * H_;
  const float* Kp = H + ((size_t)(ks*B_ + b)*T_) * H_;
  __shared__ float qr[8][H_];
  __shared__ float P[8][T_];
  __shared__ float rinv[8];
  int tid = threadIdx.x;

  for (int e = tid; e < 8*H_; e += 256) {
    int r = e / H_, m = e % H_;
    qr[r][m] = Q[(size_t)(r0 + r)*H_ + m];
  }
  __syncthreads();
  #pragma unroll
  for (int rep = 0; rep < 4; ++rep) {
    int e = tid + rep*256;
    int r = e >> 7, q = e & 127;
    float sc;
    if (q >= klen) sc = NEGV;
    else {
      sc = 0.f;
      const float* kp = Kp + (size_t)q*H_;
      #pragma unroll 4
      for (int m = 0; m < H_; ++m) sc = fmaf(qr[r][m], kp[m], sc);
    }
    P[r][q] = sc;
  }
  __syncthreads();
  {
    int g = tid >> 5, l = tid & 31;
    float s0 = P[g][l], s1 = P[g][l+32], s2 = P[g][l+64], s3 = P[g][l+96];
    float m0 = fmaxf(fmaxf(s0,s1), fmaxf(s2,s3));
    for (int o = 16; o > 0; o >>= 1) m0 = fmaxf(m0, __shfl_xor(m0, o, 32));
    float e0 = expf(s0-m0), e1 = expf(s1-m0), e2 = expf(s2-m0), e3 = expf(s3-m0);
    float sum = e0+e1+e2+e3;
    for (int o = 16; o > 0; o >>= 1) sum += __shfl_xor(sum, o, 32);
    P[g][l] = e0; P[g][l+32] = e1; P[g][l+64] = e2; P[g][l+96] = e3;
    if (l == 0) rinv[g] = 1.f / sum;
  }
  __syncthreads();
  float* out = ATT + ((size_t)(d*B_ + b)*T_ + r0) * H_;
  for (int e = tid; e < 8*H_; e += 256) {
    int r = e / H_, h = e % H_;
    float a = 0.f;
    const float* kp = Kp + h;
    #pragma unroll 4
    for (int q = 0; q < T_; ++q) a = fmaf(P[r][q], kp[(size_t)q*H_], a);
    out[(size_t)r*H_ + h] = a * rinv[r];
  }
}

// ---------------- enhance: [enc, att, enc-att, enc*att] ----------------
__global__ __launch_bounds__(256) void k_enhance(const float* __restrict__ H, const float* __restrict__ ATT,
    float* __restrict__ ENH)
{
  size_t i = (size_t)blockIdx.x*256 + threadIdx.x;   // over 2*4096*1200
  int col = (int)(i % HG);
  size_t sbt = i / HG;
  int g = col / H_, k = col % H_;
  float e = H[sbt*H_ + k], a = ATT[sbt*H_ + k];
  float r = (g==0) ? e : (g==1) ? a : (g==2) ? (e - a) : (e * a);
  ENH[i] = r;
}

// ---------------- pool + classifier ----------------
__global__ __launch_bounds__(256) void k_pool_classify(const float* __restrict__ H,  // comp h (2,B,T,300)
    const int* __restrict__ plen, const int* __restrict__ hlen,
    const float* __restrict__ w1, const float* __restrict__ b1,
    const float* __restrict__ w2, const float* __restrict__ b2,
    float* __restrict__ out)
{
  int b = blockIdx.x;
  __shared__ float v[2*HG/2];      // 1200
  __shared__ float hid[H_];
  int tid = threadIdx.x;
  for (int s = 0; s < 2; ++s) {
    int len = (s==0 ? plen[b] : hlen[b]);
    const float* hp = H + (size_t)(s*B_+b)*T_*H_;
    for (int k = tid; k < H_; k += 256) {
      float sum = 0.f, mx = NEGV;
      for (int t = 0; t < T_; ++t) {
        float x = hp[(size_t)t*H_ + k];
        if (t < len) { sum += x; mx = fmaxf(mx, x); }
      }
      v[s*600 + k]       = sum / (float)len;
      v[s*600 + 300 + k] = mx;
    }
  }
  __syncthreads();
  for (int k = tid; k < H_; k += 256) {
    float a = b1[k];
    const float* wr = w1 + (size_t)k*HG;
    #pragma unroll 4
    for (int m = 0; m < HG; ++m) a = fmaf(v[m], wr[m], a);
    hid[k] = tanhf(a);
  }
  __syncthreads();
  if (tid < 3) {
    float a = b2[tid];
    const float* wr = w2 + (size_t)tid*H_;
    for (int n = 0; n < H_; ++n) a = fmaf(hid[n], wr[n], a);
    out[b*3 + tid] = a;
  }
}

// ---------------- launch ----------------
extern "C" void kernel_launch(void* const* d_in, const int* in_sizes, int n_in,
                              void* d_out, int out_size, void* d_ws, size_t ws_size,
                              hipStream_t stream) {
  const int*   prem    = (const int*)d_in[0];
  const int*   plen    = (const int*)d_in[1];
  const int*   hyp     = (const int*)d_in[2];
  const int*   hlen    = (const int*)d_in[3];
  const float* lg      = (const float*)d_in[4];
  const float* rg      = (const float*)d_in[5];
  const float* emb     = (const float*)d_in[6];
  const float* enc_wx  = (const float*)d_in[7];
  const float* enc_bx  = (const float*)d_in[8];
  const float* enc_uh  = (const float*)d_in[9];
  const float* enc_bh  = (const float*)d_in[10];
  const float* comp_wx = (const float*)d_in[11];
  const float* comp_bx = (const float*)d_in[12];
  const float* comp_uh = (const float*)d_in[13];
  const float* comp_bh = (const float*)d_in[14];
  const float* proj_w  = (const float*)d_in[15];
  const float* proj_b  = (const float*)d_in[16];
  const float* cls_w1  = (const float*)d_in[17];
  const float* cls_b1  = (const float*)d_in[18];
  const float* cls_w2  = (const float*)d_in[19];
  const float* cls_b2  = (const float*)d_in[20];
  float* outp = (float*)d_out;

  // workspace layout (floats)
  const size_t SZ_XG  = (size_t)2*B_*T_*HG;   // 9,830,400  (enc-xg -> enh -> comp-xg)
  const size_t SZ_BTH = (size_t)2*B_*T_*H_;   // 2,457,600
  float* XG  = (float*)d_ws;
  float* EMB = XG  + SZ_XG;     // embeddings -> proj
  float* H1  = EMB + SZ_BTH;    // enc h -> comp h
  float* CH  = H1  + SZ_BTH;    // c history
  float* FH  = CH  + SZ_BTH;    // fh = uh1 @ h
  float* ATT = FH  + SZ_BTH;
  float* UTE = ATT + SZ_BTH;    // uh1T enc (90000)
  float* UTC = UTE + (size_t)H_*H_;
  int*   HASP = (int*)(UTC + (size_t)H_*H_);

  // 1. embeddings
  k_embed<<<2400, 256, 0, stream>>>(prem, hyp, emb, EMB);
  // 2. weight prep
  k_prep_uh1T<<<(H_*H_ + 255)/256, 256, 0, stream>>>(enc_uh, comp_uh, UTE, UTC);
  k_hasp<<<64, 128, 0, stream>>>(lg, rg, HASP);
  // 3. enc xg = emb @ enc_wx^T + enc_bx
  k_gemm_nt<<<dim3(10, 64), 256, 0, stream>>>(EMB, enc_wx, enc_bx, XG, 2*B_*T_, HG, H_, 0);
  // 4. enc tree scan
  k_tree_scan<<<64, 320, 0, stream>>>(XG, enc_bh, UTE, lg, rg, HASP, H1, CH, FH);
  // 5. attention both directions
  k_attention<<<dim3(2, B_, T_/8), 256, 0, stream>>>(H1, plen, hlen, ATT);
  // 6. enhance -> XG (enc-xg dead)
  k_enhance<<<(unsigned)((SZ_XG)/256), 256, 0, stream>>>(H1, ATT, XG);
  // 7. proj = relu(enh @ proj_w^T + proj_b) -> EMB (embeddings dead)
  k_gemm_nt<<<dim3(3, 64), 256, 0, stream>>>(XG, proj_w, proj_b, EMB, 2*B_*T_, H_, HG, 1);
  // 8. comp xg = proj @ comp_wx^T + comp_bx -> XG (enh dead)
  k_gemm_nt<<<dim3(10, 64), 256, 0, stream>>>(EMB, comp_wx, comp_bx, XG, 2*B_*T_, HG, H_, 0);
  // 9. comp tree scan -> H1 (enc h dead)
  k_tree_scan<<<64, 320, 0, stream>>>(XG, comp_bh, UTC, lg, rg, HASP, H1, CH, FH);
  // 10. pool + classifier
  k_pool_classify<<<B_, 256, 0, stream>>>(H1, plen, hlen, cls_w1, cls_b1, cls_w2, cls_b2, outp);
}

// Round 2
// 1451.361 us; speedup vs baseline: 1.5837x; 1.5837x over previous
//
#include <hip/hip_runtime.h>
#include <math.h>

#define B_ 32
#define T_ 128
#define H_ 300
#define HG 1200   // 4*H

__device__ __forceinline__ float sigm(float x){ return 1.f/(1.f+expf(-x)); }

// ---------------- embedding gather ----------------
__global__ __launch_bounds__(256) void k_embed(const int* __restrict__ prem, const int* __restrict__ hyp,
    const float* __restrict__ emb, float* __restrict__ X)
{
  int i = blockIdx.x*256 + threadIdx.x;     // over 2*B*T*75 float4s
  const int TOT = 2*B_*T_*75;
  if (i >= TOT) return;
  int f4 = i % 75;
  int bt = i / 75;          // 0..8191
  int side = bt >> 12;      // /4096
  int bt2 = bt & 4095;
  int tok = (side==0 ? prem : hyp)[bt2];
  float4 v = ((const float4*)(emb + (size_t)tok*H_))[f4];
  ((float4*)(X + (size_t)bt*H_))[f4] = v;
}

// ---------------- weight prep: uh[1] transpose ----------------
__global__ __launch_bounds__(256) void k_prep_uh1T(const float* __restrict__ enc_uh, const float* __restrict__ comp_uh,
    float* __restrict__ te, float* __restrict__ tc)
{
  int i = blockIdx.x*256 + threadIdx.x;
  if (i >= H_*H_) return;
  int m = i / H_, k = i % H_;
  te[i] = enc_uh[H_*H_ + (size_t)k*H_ + m];   // te[m][k] = uh1[k][m]
  tc[i] = comp_uh[H_*H_ + (size_t)k*H_ + m];
}

// ---------------- generic fp32 GEMM: C[M,N] = act(A[M,K] @ W[N,K]^T + bias[N]) ----------------
#define BKT 16
__global__ __launch_bounds__(256) void k_gemm_nt(const float* __restrict__ A, const float* __restrict__ W,
    const float* __restrict__ bias, float* __restrict__ C, int M, int N, int K, int act)
{
  __shared__ float As[BKT][132];
  __shared__ float Ws[BKT][132];
  int bn = blockIdx.x * 128;
  int bm = blockIdx.y * 128;
  int tid = threadIdx.x;
  int tx = tid & 15, ty = tid >> 4;
  float acc[8][8];
  #pragma unroll
  for (int i = 0; i < 8; ++i)
    #pragma unroll
    for (int j = 0; j < 8; ++j) acc[i][j] = 0.f;

  for (int k0 = 0; k0 < K; k0 += BKT) {
    int kk = (tid & 3) * 4;
    int row = tid >> 2;       // 0..63
    #pragma unroll
    for (int r = 0; r < 2; ++r) {
      int m = row + r*64;
      int gk = k0 + kk;
      float4 v = make_float4(0.f,0.f,0.f,0.f);
      if (bm + m < M) {
        const float* ap = A + (size_t)(bm+m)*K + gk;
        if (gk + 3 < K) v = *(const float4*)ap;
        else { if (gk<K) v.x=ap[0]; if (gk+1<K) v.y=ap[1]; if (gk+2<K) v.z=ap[2]; if (gk+3<K) v.w=ap[3]; }
      }
      As[kk+0][m]=v.x; As[kk+1][m]=v.y; As[kk+2][m]=v.z; As[kk+3][m]=v.w;
      int n = row + r*64;
      float4 w = make_float4(0.f,0.f,0.f,0.f);
      if (bn + n < N) {
        const float* wp = W + (size_t)(bn+n)*K + gk;
        if (gk + 3 < K) w = *(const float4*)wp;
        else { if (gk<K) w.x=wp[0]; if (gk+1<K) w.y=wp[1]; if (gk+2<K) w.z=wp[2]; if (gk+3<K) w.w=wp[3]; }
      }
      Ws[kk+0][n]=w.x; Ws[kk+1][n]=w.y; Ws[kk+2][n]=w.z; Ws[kk+3][n]=w.w;
    }
    __syncthreads();
    #pragma unroll
    for (int kk2 = 0; kk2 < BKT; ++kk2) {
      float a[8], b[8];
      *(float4*)&a[0] = *(const float4*)&As[kk2][ty*8];
      *(float4*)&a[4] = *(const float4*)&As[kk2][ty*8+4];
      *(float4*)&b[0] = *(const float4*)&Ws[kk2][tx*8];
      *(float4*)&b[4] = *(const float4*)&Ws[kk2][tx*8+4];
      #pragma unroll
      for (int i = 0; i < 8; ++i)
        #pragma unroll
        for (int j = 0; j < 8; ++j) acc[i][j] = fmaf(a[i], b[j], acc[i][j]);
    }
    __syncthreads();
  }
  #pragma unroll
  for (int i = 0; i < 8; ++i) {
    int m = bm + ty*8 + i;
    if (m >= M) continue;
    #pragma unroll
    for (int j = 0; j < 8; ++j) {
      int n = bn + tx*8 + j;
      if (n >= N) continue;
      float v = acc[i][j] + bias[n];
      if (act == 1) v = fmaxf(v, 0.f);
      C[(size_t)m*N + n] = v;
    }
  }
}

// ---------------- level-parallel tree-LSTM: one block per (side,batch) chain ----------------
// Dependency DAG depth ~5 for 1% graph density -> process whole levels in parallel.
#define ECAP 4096
__global__ __launch_bounds__(1024) void k_tree_scan_lvl(
    const float* __restrict__ xg,   // (2,B,T,1200)
    const float* __restrict__ bhv,  // (4,300)
    const float* __restrict__ uh1T, // (300,300) [m][k] = uh1[k][m]
    const float* __restrict__ lg, const float* __restrict__ rg,
    float* __restrict__ hout, float* __restrict__ chist, float* __restrict__ fh)
{
  int chain = blockIdx.x; int s = chain >> 5, b = chain & 31;
  const float* graph = (s ? rg : lg) + (size_t)b*T_*T_;
  int tid = threadIdx.x;

  __shared__ float bh_s[4][H_];
  __shared__ int cnt[T_], coff[T_], depth[T_], order[T_], flist[T_], hasp_s[T_];
  __shared__ short eidx[ECAP];
  __shared__ float ew[ECAP];
  __shared__ int lcnt[T_], lpos[T_], lvl_off[T_+1];
  __shared__ int maxd_s, fcnt_s;

  // ---- stage bh, init counters ----
  for (int i = tid; i < 4*H_; i += 1024) { int g = i/H_; bh_s[g][i - g*H_] = bhv[i]; }
  if (tid < T_) { lcnt[tid] = 0; hasp_s[tid] = 0; }
  // ---- count children (strictly earlier positions; later ones multiply c=0) ----
  if (tid < T_) {
    int j = tid, c = 0;
    const float* gr = graph + (size_t)j*T_;
    for (int t = 0; t < j; ++t) c += (gr[t] != 0.f) ? 1 : 0;
    cnt[j] = c;
  }
  __syncthreads();
  if (tid == 0) { int a = 0; for (int j = 0; j < T_; ++j) { coff[j] = a; a += cnt[j]; } }
  __syncthreads();
  // ---- fill edge lists + parent flags ----
  if (tid < T_) {
    int j = tid, p = coff[j];
    const float* gr = graph + (size_t)j*T_;
    for (int t = 0; t < j; ++t) {
      float g = gr[t];
      if (g != 0.f) { eidx[p] = (short)t; ew[p] = g; hasp_s[t] = 1; ++p; }
    }
  }
  __syncthreads();
  // ---- node depths (serial; ~#edges ops total) ----
  if (tid == 0) {
    int md = 0;
    for (int j = 0; j < T_; ++j) {
      int d = 0, e0 = coff[j], e1 = coff[j] + cnt[j];
      for (int k = e0; k < e1; ++k) { int dd = depth[eidx[k]] + 1; d = dd > d ? dd : d; }
      depth[j] = d; md = d > md ? d : md;
    }
    maxd_s = md;
  }
  __syncthreads();
  if (tid < T_) atomicAdd(&lcnt[depth[tid]], 1);
  __syncthreads();
  int maxd = maxd_s;
  if (tid == 0) { int a = 0; for (int l = 0; l <= maxd; ++l) { lvl_off[l] = a; a += lcnt[l]; } lvl_off[maxd+1] = a; }
  __syncthreads();
  if (tid <= maxd) lpos[tid] = lvl_off[tid];
  __syncthreads();
  if (tid < T_) { int p = atomicAdd(&lpos[depth[tid]], 1); order[p] = tid; }
  __syncthreads();

  size_t cb = (size_t)chain * T_ * H_;
  size_t xb = (size_t)chain * T_ * HG;

  // ---- process levels ----
  for (int lvl = 0; lvl <= maxd; ++lvl) {
    int lo = lvl_off[lvl], hi = lvl_off[lvl+1];
    int nl = hi - lo;
    if (tid == 0) fcnt_s = 0;
    __syncthreads();
    if (tid < nl) {
      int j = order[lo + tid];
      if (hasp_s[j]) { int p = atomicAdd(&fcnt_s, 1); flist[p] = j; }
    }
    // gates + child accumulation for all nodes in this level
    for (int w = tid; w < nl*H_; w += 1024) {
      int n = w / H_, e = w - n*H_;
      int j = order[lo + n];
      const float* xp = xg + xb + (size_t)j*HG;
      float x0 = xp[e], x1 = xp[H_+e], x2 = xp[2*H_+e], x3 = xp[3*H_+e];
      float iu  = sigm(x0 + bh_s[0][e]) * tanhf(x3 + bh_s[3][e]);
      float og  = sigm(x2 + bh_s[2][e]);
      float x1b = x1 + bh_s[1][e];
      float acc = iu;
      int e1 = coff[j] + cnt[j];
      for (int k = coff[j]; k < e1; ++k) {
        int t = eidx[k];
        float fv = fh[cb + (size_t)t*H_ + e];
        float cv = chist[cb + (size_t)t*H_ + e];
        acc += ew[k] * sigm(x1b + fv) * cv;
      }
      chist[cb + (size_t)j*H_ + e] = acc;
      hout[cb + (size_t)j*H_ + e] = og * tanhf(acc);
    }
    __syncthreads();
    // fh = uh1 @ h for this level's parented nodes, 4-node register blocking
    int fc = fcnt_s;
    if (tid < 3*H_ && fc > 0) {
      int grp = tid / H_;             // 0..2
      int e = tid - grp*H_;
      for (int base = grp*4; base < fc; base += 12) {
        int j0 = flist[base];
        int j1 = (base+1 < fc) ? flist[base+1] : j0;
        int j2 = (base+2 < fc) ? flist[base+2] : j0;
        int j3 = (base+3 < fc) ? flist[base+3] : j0;
        const float* h0 = hout + cb + (size_t)j0*H_;
        const float* h1 = hout + cb + (size_t)j1*H_;
        const float* h2 = hout + cb + (size_t)j2*H_;
        const float* h3 = hout + cb + (size_t)j3*H_;
        float a0=0.f, a1=0.f, a2=0.f, a3=0.f;
        const float* up = uh1T + e;
        #pragma unroll 4
        for (int m = 0; m < H_; ++m) {
          float u = up[(size_t)m*H_];
          a0 = fmaf(u, h0[m], a0);
          a1 = fmaf(u, h1[m], a1);
          a2 = fmaf(u, h2[m], a2);
          a3 = fmaf(u, h3[m], a3);
        }
        fh[cb + (size_t)j0*H_ + e] = a0;
        if (base+1 < fc) fh[cb + (size_t)j1*H_ + e] = a1;
        if (base+2 < fc) fh[cb + (size_t)j2*H_ + e] = a2;
        if (base+3 < fc) fh[cb + (size_t)j3*H_ + e] = a3;
      }
    }
    __syncthreads();
  }
}

// ---------------- fused attention (one direction per blockIdx.x) ----------------
#define NEGV -10000000.0f
__global__ __launch_bounds__(256) void k_attention(const float* __restrict__ H,  // (2,B,T,300)
    const int* __restrict__ plen, const int* __restrict__ hlen, float* __restrict__ ATT)
{
  int d = blockIdx.x;          // 0: q=enc_p,k=enc_h,mask=hlen ; 1: q=enc_h,k=enc_p,mask=plen
  int b = blockIdx.y;
  int r0 = blockIdx.z * 8;
  int qs = d, ks = 1 - d;
  int klen = (d == 0 ? hlen[b] : plen[b]);
  const float* Q  = H + ((size_t)(qs*B_ + b)*T_) * H_;
  const float* Kp = H + ((size_t)(ks*B_ + b)*T_) * H_;
  __shared__ float qr[8][H_];
  __shared__ float P[8][T_];
  __shared__ float rinv[8];
  int tid = threadIdx.x;

  for (int e = tid; e < 8*H_; e += 256) {
    int r = e / H_, m = e % H_;
    qr[r][m] = Q[(size_t)(r0 + r)*H_ + m];
  }
  __syncthreads();
  #pragma unroll
  for (int rep = 0; rep < 4; ++rep) {
    int e = tid + rep*256;
    int r = e >> 7, q = e & 127;
    float sc;
    if (q >= klen) sc = NEGV;
    else {
      sc = 0.f;
      const float* kp = Kp + (size_t)q*H_;
      #pragma unroll 4
      for (int m = 0; m < H_; ++m) sc = fmaf(qr[r][m], kp[m], sc);
    }
    P[r][q] = sc;
  }
  __syncthreads();
  {
    int g = tid >> 5, l = tid & 31;
    float s0 = P[g][l], s1 = P[g][l+32], s2 = P[g][l+64], s3 = P[g][l+96];
    float m0 = fmaxf(fmaxf(s0,s1), fmaxf(s2,s3));
    for (int o = 16; o > 0; o >>= 1) m0 = fmaxf(m0, __shfl_xor(m0, o, 32));
    float e0 = expf(s0-m0), e1 = expf(s1-m0), e2 = expf(s2-m0), e3 = expf(s3-m0);
    float sum = e0+e1+e2+e3;
    for (int o = 16; o > 0; o >>= 1) sum += __shfl_xor(sum, o, 32);
    P[g][l] = e0; P[g][l+32] = e1; P[g][l+64] = e2; P[g][l+96] = e3;
    if (l == 0) rinv[g] = 1.f / sum;
  }
  __syncthreads();
  float* out = ATT + ((size_t)(d*B_ + b)*T_ + r0) * H_;
  for (int e = tid; e < 8*H_; e += 256) {
    int r = e / H_, h = e % H_;
    float a = 0.f;
    const float* kp = Kp + h;
    #pragma unroll 4
    for (int q = 0; q < T_; ++q) a = fmaf(P[r][q], kp[(size_t)q*H_], a);
    out[(size_t)r*H_ + h] = a * rinv[r];
  }
}

// ---------------- enhance: [enc, att, enc-att, enc*att] ----------------
__global__ __launch_bounds__(256) void k_enhance(const float* __restrict__ H, const float* __restrict__ ATT,
    float* __restrict__ ENH)
{
  size_t i = (size_t)blockIdx.x*256 + threadIdx.x;   // over 2*4096*1200
  int col = (int)(i % HG);
  size_t sbt = i / HG;
  int g = col / H_, k = col % H_;
  float e = H[sbt*H_ + k], a = ATT[sbt*H_ + k];
  float r = (g==0) ? e : (g==1) ? a : (g==2) ? (e - a) : (e * a);
  ENH[i] = r;
}

// ---------------- pool + classifier ----------------
__global__ __launch_bounds__(256) void k_pool_classify(const float* __restrict__ H,  // comp h (2,B,T,300)
    const int* __restrict__ plen, const int* __restrict__ hlen,
    const float* __restrict__ w1, const float* __restrict__ b1,
    const float* __restrict__ w2, const float* __restrict__ b2,
    float* __restrict__ out)
{
  int b = blockIdx.x;
  __shared__ float v[HG];          // 1200
  __shared__ float hid[H_];
  int tid = threadIdx.x;
  for (int s = 0; s < 2; ++s) {
    int len = (s==0 ? plen[b] : hlen[b]);
    const float* hp = H + (size_t)(s*B_+b)*T_*H_;
    for (int k = tid; k < H_; k += 256) {
      float sum = 0.f, mx = NEGV;
      for (int t = 0; t < T_; ++t) {
        float x = hp[(size_t)t*H_ + k];
        if (t < len) { sum += x; mx = fmaxf(mx, x); }
      }
      v[s*600 + k]       = sum / (float)len;
      v[s*600 + 300 + k] = mx;
    }
  }
  __syncthreads();
  for (int k = tid; k < H_; k += 256) {
    float a = b1[k];
    const float* wr = w1 + (size_t)k*HG;
    #pragma unroll 4
    for (int m = 0; m < HG; ++m) a = fmaf(v[m], wr[m], a);
    hid[k] = tanhf(a);
  }
  __syncthreads();
  if (tid < 3) {
    float a = b2[tid];
    const float* wr = w2 + (size_t)tid*H_;
    for (int n = 0; n < H_; ++n) a = fmaf(hid[n], wr[n], a);
    out[b*3 + tid] = a;
  }
}

// ---------------- launch ----------------
extern "C" void kernel_launch(void* const* d_in, const int* in_sizes, int n_in,
                              void* d_out, int out_size, void* d_ws, size_t ws_size,
                              hipStream_t stream) {
  const int*   prem    = (const int*)d_in[0];
  const int*   plen    = (const int*)d_in[1];
  const int*   hyp     = (const int*)d_in[2];
  const int*   hlen    = (const int*)d_in[3];
  const float* lg      = (const float*)d_in[4];
  const float* rg      = (const float*)d_in[5];
  const float* emb     = (const float*)d_in[6];
  const float* enc_wx  = (const float*)d_in[7];
  const float* enc_bx  = (const float*)d_in[8];
  const float* enc_uh  = (const float*)d_in[9];
  const float* enc_bh  = (const float*)d_in[10];
  const float* comp_wx = (const float*)d_in[11];
  const float* comp_bx = (const float*)d_in[12];
  const float* comp_uh = (const float*)d_in[13];
  const float* comp_bh = (const float*)d_in[14];
  const float* proj_w  = (const float*)d_in[15];
  const float* proj_b  = (const float*)d_in[16];
  const float* cls_w1  = (const float*)d_in[17];
  const float* cls_b1  = (const float*)d_in[18];
  const float* cls_w2  = (const float*)d_in[19];
  const float* cls_b2  = (const float*)d_in[20];
  float* outp = (float*)d_out;

  // workspace layout (floats)
  const size_t SZ_XG  = (size_t)2*B_*T_*HG;   // 9,830,400  (enc-xg -> enh -> comp-xg)
  const size_t SZ_BTH = (size_t)2*B_*T_*H_;   // 2,457,600
  float* XG  = (float*)d_ws;
  float* EMB = XG  + SZ_XG;     // embeddings -> proj
  float* H1  = EMB + SZ_BTH;    // enc h -> comp h
  float* CH  = H1  + SZ_BTH;    // c history
  float* FH  = CH  + SZ_BTH;    // fh = uh1 @ h
  float* ATT = FH  + SZ_BTH;
  float* UTE = ATT + SZ_BTH;    // uh1T enc (90000)
  float* UTC = UTE + (size_t)H_*H_;

  // 1. embeddings
  k_embed<<<2400, 256, 0, stream>>>(prem, hyp, emb, EMB);
  // 2. weight prep
  k_prep_uh1T<<<(H_*H_ + 255)/256, 256, 0, stream>>>(enc_uh, comp_uh, UTE, UTC);
  // 3. enc xg = emb @ enc_wx^T + enc_bx
  k_gemm_nt<<<dim3(10, 64), 256, 0, stream>>>(EMB, enc_wx, enc_bx, XG, 2*B_*T_, HG, H_, 0);
  // 4. enc tree scan (level-parallel)
  k_tree_scan_lvl<<<64, 1024, 0, stream>>>(XG, enc_bh, UTE, lg, rg, H1, CH, FH);
  // 5. attention both directions
  k_attention<<<dim3(2, B_, T_/8), 256, 0, stream>>>(H1, plen, hlen, ATT);
  // 6. enhance -> XG (enc-xg dead)
  k_enhance<<<(unsigned)((SZ_XG)/256), 256, 0, stream>>>(H1, ATT, XG);
  // 7. proj = relu(enh @ proj_w^T + proj_b) -> EMB (embeddings dead)
  k_gemm_nt<<<dim3(3, 64), 256, 0, stream>>>(XG, proj_w, proj_b, EMB, 2*B_*T_, H_, HG, 1);
  // 8. comp xg = proj @ comp_wx^T + comp_bx -> XG (enh dead)
  k_gemm_nt<<<dim3(10, 64), 256, 0, stream>>>(EMB, comp_wx, comp_bx, XG, 2*B_*T_, HG, H_, 0);
  // 9. comp tree scan -> H1 (enc h dead)
  k_tree_scan_lvl<<<64, 1024, 0, stream>>>(XG, comp_bh, UTC, lg, rg, H1, CH, FH);
  // 10. pool + classifier
  k_pool_classify<<<B_, 256, 0, stream>>>(H1, plen, hlen, cls_w1, cls_b1, cls_w2, cls_b2, outp);
}

// Round 3
// 1165.232 us; speedup vs baseline: 1.9726x; 1.2456x over previous
//
#include <hip/hip_runtime.h>
#include <math.h>

#define B_ 32
#define T_ 128
#define H_ 300
#define HG 1200   // 4*H
#define LMAX 10
#define WLCAP 8192
#define ECAP 2048

__device__ __forceinline__ float sigm(float x){ return 1.f/(1.f+expf(-x)); }

// ---------------- embedding gather ----------------
__global__ __launch_bounds__(256) void k_embed(const int* __restrict__ prem, const int* __restrict__ hyp,
    const float* __restrict__ emb, float* __restrict__ X)
{
  int i = blockIdx.x*256 + threadIdx.x;     // over 2*B*T*75 float4s
  const int TOT = 2*B_*T_*75;
  if (i >= TOT) return;
  int f4 = i % 75;
  int bt = i / 75;          // 0..8191
  int side = bt >> 12;      // /4096
  int bt2 = bt & 4095;
  int tok = (side==0 ? prem : hyp)[bt2];
  float4 v = ((const float4*)(emb + (size_t)tok*H_))[f4];
  ((float4*)(X + (size_t)bt*H_))[f4] = v;
}

// ---------------- weight prep: uh[1] transpose ----------------
__global__ __launch_bounds__(256) void k_prep_uh1T(const float* __restrict__ enc_uh, const float* __restrict__ comp_uh,
    float* __restrict__ te, float* __restrict__ tc)
{
  int i = blockIdx.x*256 + threadIdx.x;
  if (i >= H_*H_) return;
  int m = i / H_, k = i % H_;
  te[i] = enc_uh[H_*H_ + (size_t)k*H_ + m];   // te[m][k] = uh1[k][m]
  tc[i] = comp_uh[H_*H_ + (size_t)k*H_ + m];
}

// ---------------- graph analysis: edges, depths, level worklists (shared by both scans) ----------------
__global__ __launch_bounds__(256) void k_build(const float* __restrict__ lg, const float* __restrict__ rg,
    int* __restrict__ cnt_g, int* __restrict__ coff_g, int* __restrict__ eidx_g, float* __restrict__ ew_g,
    int* __restrict__ hasp_g, int* __restrict__ depth_g, int* __restrict__ maxd_g,
    int* __restrict__ lvlcnt_g, int* __restrict__ wl_g)
{
  int chain = blockIdx.x; int s = chain >> 5, b = chain & 31;
  const float* graph = (s ? rg : lg) + (size_t)b*T_*T_;
  int tid = threadIdx.x;
  __shared__ int cnt[T_], coff[T_], depth[T_], hasp[T_];
  __shared__ short eidx[ECAP];
  __shared__ float ew[ECAP];
  __shared__ int etot_s;
  if (tid < T_) hasp[tid] = 0;
  if (tid < T_) {
    int j = tid, c = 0;
    const float* gr = graph + (size_t)j*T_;
    for (int t = 0; t < j; ++t) c += (gr[t] != 0.f) ? 1 : 0;
    cnt[j] = c;
  }
  __syncthreads();
  if (tid == 0) { int a = 0; for (int j = 0; j < T_; ++j) { coff[j] = a; a += cnt[j]; } etot_s = a; }
  __syncthreads();
  if (tid < T_) {
    int j = tid, p = coff[j];
    const float* gr = graph + (size_t)j*T_;
    for (int t = 0; t < j; ++t) {
      float g = gr[t];
      if (g != 0.f && p < ECAP) { eidx[p] = (short)t; ew[p] = g; hasp[t] = 1; ++p; }
    }
  }
  __syncthreads();
  if (tid == 0) {
    int md = 0;
    for (int j = 0; j < T_; ++j) {
      int d = 0, e0 = coff[j], e1 = coff[j] + cnt[j];
      if (e1 > ECAP) e1 = ECAP;
      for (int k = e0; k < e1; ++k) { int dd = depth[eidx[k]] + 1; d = dd > d ? dd : d; }
      depth[j] = d; md = d > md ? d : md;
    }
    maxd_g[chain] = md;
  }
  __syncthreads();
  int base = chain * T_;
  if (tid < T_) {
    cnt_g[base+tid] = cnt[tid]; coff_g[base+tid] = coff[tid];
    hasp_g[base+tid] = hasp[tid]; depth_g[base+tid] = depth[tid];
    int L = depth[tid];
    if (L < LMAX) { int p = atomicAdd(&lvlcnt_g[L], 1); wl_g[L*WLCAP + p] = (chain << 8) | tid; }
  }
  int etot = etot_s; if (etot > ECAP) etot = ECAP;
  for (int i = tid; i < etot; i += 256) { eidx_g[chain*ECAP + i] = eidx[i]; ew_g[chain*ECAP + i] = ew[i]; }
}

// ---------------- per-level tree-LSTM: 4 nodes per block, all CUs ----------------
__global__ __launch_bounds__(1024) void k_level(
    const float* __restrict__ xg,   // (2,B,T,1200)
    const float* __restrict__ bhv,  // (4,300)
    const float* __restrict__ uh1T, // (300,300) [m][k] = uh1[k][m]
    const int* __restrict__ cnt_g, const int* __restrict__ coff_g,
    const int* __restrict__ eidx_g, const float* __restrict__ ew_g,
    const int* __restrict__ hasp_g, const int* __restrict__ lvlcnt_g, const int* __restrict__ wl_g,
    int L, float* __restrict__ hout, float* __restrict__ chist, float* __restrict__ fh)
{
  int count = lvlcnt_g[L];
  int nblk = (count + 3) >> 2;
  int tid = threadIdx.x;
  __shared__ float h_s[4][H_];
  __shared__ float psum[3][4][H_];
  __shared__ int nodes[4];
  __shared__ int anyp;
  for (int blk = blockIdx.x; blk < nblk; blk += gridDim.x) {
    int base = blk * 4;
    int nn = count - base; if (nn > 4) nn = 4;
    if (tid == 0) anyp = 0;
    __syncthreads();
    if (tid < 4) {
      int pk = (tid < nn) ? wl_g[L*WLCAP + base + tid] : -1;
      nodes[tid] = pk;
      if (pk >= 0 && hasp_g[(pk >> 8)*T_ + (pk & 255)]) atomicAdd(&anyp, 1);
    }
    __syncthreads();
    // gates + child accumulation
    for (int w = tid; w < nn*H_; w += 1024) {
      int n = w / H_, e = w - n*H_;
      int pk = nodes[n]; int chain = pk >> 8, j = pk & 255;
      size_t cb = (size_t)chain*T_*H_, xb = (size_t)chain*T_*HG;
      const float* xp = xg + xb + (size_t)j*HG;
      float x0 = xp[e], x1 = xp[H_+e], x2 = xp[2*H_+e], x3 = xp[3*H_+e];
      float iu  = sigm(x0 + bhv[e]) * tanhf(x3 + bhv[3*H_+e]);
      float og  = sigm(x2 + bhv[2*H_+e]);
      float x1b = x1 + bhv[H_+e];
      float acc = iu;
      int c0 = coff_g[chain*T_+j], c1 = c0 + cnt_g[chain*T_+j];
      const int* ei = eidx_g + chain*ECAP;
      const float* ewp = ew_g + chain*ECAP;
      for (int k = c0; k < c1; ++k) {
        int t = ei[k];
        acc += ewp[k] * sigm(x1b + fh[cb + (size_t)t*H_ + e]) * chist[cb + (size_t)t*H_ + e];
      }
      chist[cb + (size_t)j*H_ + e] = acc;
      float hv = og * tanhf(acc);
      hout[cb + (size_t)j*H_ + e] = hv;
      h_s[n][e] = hv;
    }
    __syncthreads();
    if (anyp > 0) {
      // fh = uh1 @ h, 4 nodes at once; thread (g,e): m in [g*100,g*100+100)
      if (tid < 3*H_) {
        int g = tid / H_, e = tid - g*H_;
        float a0=0.f, a1=0.f, a2=0.f, a3=0.f;
        const float* up = uh1T + e;
        int m0 = g*100, m1 = m0 + 100;
        #pragma unroll 4
        for (int m = m0; m < m1; ++m) {
          float u = up[(size_t)m*H_];
          a0 = fmaf(u, h_s[0][m], a0);
          a1 = fmaf(u, h_s[1][m], a1);
          a2 = fmaf(u, h_s[2][m], a2);
          a3 = fmaf(u, h_s[3][m], a3);
        }
        psum[g][0][e]=a0; psum[g][1][e]=a1; psum[g][2][e]=a2; psum[g][3][e]=a3;
      }
      __syncthreads();
      for (int w = tid; w < nn*H_; w += 1024) {
        int n = w / H_, e = w - n*H_;
        int pk = nodes[n]; int chain = pk >> 8, j = pk & 255;
        if (hasp_g[chain*T_+j]) {
          size_t cb = (size_t)chain*T_*H_;
          fh[cb + (size_t)j*H_ + e] = psum[0][n][e] + psum[1][n][e] + psum[2][n][e];
        }
      }
    }
    __syncthreads();
  }
}

// ---------------- serial tail for rare deep graphs (depth >= LMAX) ----------------
__global__ __launch_bounds__(320) void k_tail(const float* __restrict__ xg, const float* __restrict__ bhv,
    const float* __restrict__ uh1T, const int* __restrict__ cnt_g, const int* __restrict__ coff_g,
    const int* __restrict__ eidx_g, const float* __restrict__ ew_g, const int* __restrict__ hasp_g,
    const int* __restrict__ depth_g, const int* __restrict__ maxd_g,
    float* __restrict__ hout, float* __restrict__ chist, float* __restrict__ fh)
{
  int chain = blockIdx.x;
  if (maxd_g[chain] < LMAX) return;
  int tid = threadIdx.x;
  bool act = tid < H_;
  float bh0=0.f,bh1=0.f,bh2=0.f,bh3=0.f;
  if (act) { bh0=bhv[tid]; bh1=bhv[H_+tid]; bh2=bhv[2*H_+tid]; bh3=bhv[3*H_+tid]; }
  __shared__ float h_lds[H_];
  size_t cb = (size_t)chain*T_*H_, xb = (size_t)chain*T_*HG;
  const int* ei = eidx_g + chain*ECAP;
  const float* ewp = ew_g + chain*ECAP;
  for (int j = 0; j < T_; ++j) {
    if (depth_g[chain*T_+j] < LMAX) continue;
    if (act) {
      const float* xp = xg + xb + (size_t)j*HG;
      float x0 = xp[tid], x1 = xp[H_+tid], x2 = xp[2*H_+tid], x3 = xp[3*H_+tid];
      float acc = sigm(x0+bh0) * tanhf(x3+bh3);
      float og  = sigm(x2+bh2);
      float x1b = x1 + bh1;
      int c0 = coff_g[chain*T_+j], c1 = c0 + cnt_g[chain*T_+j];
      for (int k = c0; k < c1; ++k) {
        int t = ei[k];
        acc += ewp[k] * sigm(x1b + fh[cb + (size_t)t*H_ + tid]) * chist[cb + (size_t)t*H_ + tid];
      }
      chist[cb + (size_t)j*H_ + tid] = acc;
      float hv = og * tanhf(acc);
      hout[cb + (size_t)j*H_ + tid] = hv;
      h_lds[tid] = hv;
    }
    __syncthreads();
    if (hasp_g[chain*T_+j] && act) {
      float a = 0.f;
      const float* up = uh1T + tid;
      #pragma unroll 4
      for (int m = 0; m < H_; ++m) a = fmaf(up[(size_t)m*H_], h_lds[m], a);
      fh[cb + (size_t)j*H_ + tid] = a;
    }
    __syncthreads();
  }
}

// ---------------- generic fp32 GEMM: C[M,N] = act(A[M,K] @ W[N,K]^T + bias[N]) ----------------
#define BKT 16
__global__ __launch_bounds__(256) void k_gemm_nt(const float* __restrict__ A, const float* __restrict__ W,
    const float* __restrict__ bias, float* __restrict__ C, int M, int N, int K, int act)
{
  __shared__ float As[BKT][132];
  __shared__ float Ws[BKT][132];
  int bn = blockIdx.x * 128;
  int bm = blockIdx.y * 128;
  int tid = threadIdx.x;
  int tx = tid & 15, ty = tid >> 4;
  float acc[8][8];
  #pragma unroll
  for (int i = 0; i < 8; ++i)
    #pragma unroll
    for (int j = 0; j < 8; ++j) acc[i][j] = 0.f;

  for (int k0 = 0; k0 < K; k0 += BKT) {
    int kk = (tid & 3) * 4;
    int row = tid >> 2;       // 0..63
    #pragma unroll
    for (int r = 0; r < 2; ++r) {
      int m = row + r*64;
      int gk = k0 + kk;
      float4 v = make_float4(0.f,0.f,0.f,0.f);
      if (bm + m < M) {
        const float* ap = A + (size_t)(bm+m)*K + gk;
        if (gk + 3 < K) v = *(const float4*)ap;
        else { if (gk<K) v.x=ap[0]; if (gk+1<K) v.y=ap[1]; if (gk+2<K) v.z=ap[2]; if (gk+3<K) v.w=ap[3]; }
      }
      As[kk+0][m]=v.x; As[kk+1][m]=v.y; As[kk+2][m]=v.z; As[kk+3][m]=v.w;
      int n = row + r*64;
      float4 w = make_float4(0.f,0.f,0.f,0.f);
      if (bn + n < N) {
        const float* wp = W + (size_t)(bn+n)*K + gk;
        if (gk + 3 < K) w = *(const float4*)wp;
        else { if (gk<K) w.x=wp[0]; if (gk+1<K) w.y=wp[1]; if (gk+2<K) w.z=wp[2]; if (gk+3<K) w.w=wp[3]; }
      }
      Ws[kk+0][n]=w.x; Ws[kk+1][n]=w.y; Ws[kk+2][n]=w.z; Ws[kk+3][n]=w.w;
    }
    __syncthreads();
    #pragma unroll
    for (int kk2 = 0; kk2 < BKT; ++kk2) {
      float a[8], b[8];
      *(float4*)&a[0] = *(const float4*)&As[kk2][ty*8];
      *(float4*)&a[4] = *(const float4*)&As[kk2][ty*8+4];
      *(float4*)&b[0] = *(const float4*)&Ws[kk2][tx*8];
      *(float4*)&b[4] = *(const float4*)&Ws[kk2][tx*8+4];
      #pragma unroll
      for (int i = 0; i < 8; ++i)
        #pragma unroll
        for (int j = 0; j < 8; ++j) acc[i][j] = fmaf(a[i], b[j], acc[i][j]);
    }
    __syncthreads();
  }
  #pragma unroll
  for (int i = 0; i < 8; ++i) {
    int m = bm + ty*8 + i;
    if (m >= M) continue;
    #pragma unroll
    for (int j = 0; j < 8; ++j) {
      int n = bn + tx*8 + j;
      if (n >= N) continue;
      float v = acc[i][j] + bias[n];
      if (act == 1) v = fmaxf(v, 0.f);
      C[(size_t)m*N + n] = v;
    }
  }
}

// ---------------- fused attention (one direction per blockIdx.x) ----------------
#define NEGV -10000000.0f
__global__ __launch_bounds__(256) void k_attention(const float* __restrict__ H,  // (2,B,T,300)
    const int* __restrict__ plen, const int* __restrict__ hlen, float* __restrict__ ATT)
{
  int d = blockIdx.x;          // 0: q=enc_p,k=enc_h,mask=hlen ; 1: q=enc_h,k=enc_p,mask=plen
  int b = blockIdx.y;
  int r0 = blockIdx.z * 8;
  int qs = d, ks = 1 - d;
  int klen = (d == 0 ? hlen[b] : plen[b]);
  const float* Q  = H + ((size_t)(qs*B_ + b)*T_) * H_;
  const float* Kp = H + ((size_t)(ks*B_ + b)*T_) * H_;
  __shared__ float qr[8][H_];
  __shared__ float P[8][T_];
  __shared__ float rinv[8];
  int tid = threadIdx.x;

  for (int e = tid; e < 8*H_; e += 256) {
    int r = e / H_, m = e % H_;
    qr[r][m] = Q[(size_t)(r0 + r)*H_ + m];
  }
  __syncthreads();
  #pragma unroll
  for (int rep = 0; rep < 4; ++rep) {
    int e = tid + rep*256;
    int r = e >> 7, q = e & 127;
    float sc;
    if (q >= klen) sc = NEGV;
    else {
      sc = 0.f;
      const float* kp = Kp + (size_t)q*H_;
      #pragma unroll 4
      for (int m = 0; m < H_; ++m) sc = fmaf(qr[r][m], kp[m], sc);
    }
    P[r][q] = sc;
  }
  __syncthreads();
  {
    int g = tid >> 5, l = tid & 31;
    float s0 = P[g][l], s1 = P[g][l+32], s2 = P[g][l+64], s3 = P[g][l+96];
    float m0 = fmaxf(fmaxf(s0,s1), fmaxf(s2,s3));
    for (int o = 16; o > 0; o >>= 1) m0 = fmaxf(m0, __shfl_xor(m0, o, 32));
    float e0 = expf(s0-m0), e1 = expf(s1-m0), e2 = expf(s2-m0), e3 = expf(s3-m0);
    float sum = e0+e1+e2+e3;
    for (int o = 16; o > 0; o >>= 1) sum += __shfl_xor(sum, o, 32);
    P[g][l] = e0; P[g][l+32] = e1; P[g][l+64] = e2; P[g][l+96] = e3;
    if (l == 0) rinv[g] = 1.f / sum;
  }
  __syncthreads();
  float* out = ATT + ((size_t)(d*B_ + b)*T_ + r0) * H_;
  for (int e = tid; e < 8*H_; e += 256) {
    int r = e / H_, h = e % H_;
    float a = 0.f;
    const float* kp = Kp + h;
    #pragma unroll 4
    for (int q = 0; q < T_; ++q) a = fmaf(P[r][q], kp[(size_t)q*H_], a);
    out[(size_t)r*H_ + h] = a * rinv[r];
  }
}

// ---------------- enhance: [enc, att, enc-att, enc*att] ----------------
__global__ __launch_bounds__(256) void k_enhance(const float* __restrict__ H, const float* __restrict__ ATT,
    float* __restrict__ ENH)
{
  size_t i = (size_t)blockIdx.x*256 + threadIdx.x;   // over 2*4096*1200
  int col = (int)(i % HG);
  size_t sbt = i / HG;
  int g = col / H_, k = col % H_;
  float e = H[sbt*H_ + k], a = ATT[sbt*H_ + k];
  float r = (g==0) ? e : (g==1) ? a : (g==2) ? (e - a) : (e * a);
  ENH[i] = r;
}

// ---------------- pool + classifier ----------------
__global__ __launch_bounds__(256) void k_pool_classify(const float* __restrict__ H,  // comp h (2,B,T,300)
    const int* __restrict__ plen, const int* __restrict__ hlen,
    const float* __restrict__ w1, const float* __restrict__ b1,
    const float* __restrict__ w2, const float* __restrict__ b2,
    float* __restrict__ out)
{
  int b = blockIdx.x;
  __shared__ float v[HG];          // 1200
  __shared__ float hid[H_];
  int tid = threadIdx.x;
  for (int s = 0; s < 2; ++s) {
    int len = (s==0 ? plen[b] : hlen[b]);
    const float* hp = H + (size_t)(s*B_+b)*T_*H_;
    for (int k = tid; k < H_; k += 256) {
      float sum = 0.f, mx = NEGV;
      for (int t = 0; t < T_; ++t) {
        float x = hp[(size_t)t*H_ + k];
        if (t < len) { sum += x; mx = fmaxf(mx, x); }
      }
      v[s*600 + k]       = sum / (float)len;
      v[s*600 + 300 + k] = mx;
    }
  }
  __syncthreads();
  for (int k = tid; k < H_; k += 256) {
    float a = b1[k];
    const float* wr = w1 + (size_t)k*HG;
    #pragma unroll 4
    for (int m = 0; m < HG; ++m) a = fmaf(v[m], wr[m], a);
    hid[k] = tanhf(a);
  }
  __syncthreads();
  if (tid < 3) {
    float a = b2[tid];
    const float* wr = w2 + (size_t)tid*H_;
    for (int n = 0; n < H_; ++n) a = fmaf(hid[n], wr[n], a);
    out[b*3 + tid] = a;
  }
}

// ---------------- launch ----------------
extern "C" void kernel_launch(void* const* d_in, const int* in_sizes, int n_in,
                              void* d_out, int out_size, void* d_ws, size_t ws_size,
                              hipStream_t stream) {
  const int*   prem    = (const int*)d_in[0];
  const int*   plen    = (const int*)d_in[1];
  const int*   hyp     = (const int*)d_in[2];
  const int*   hlen    = (const int*)d_in[3];
  const float* lg      = (const float*)d_in[4];
  const float* rg      = (const float*)d_in[5];
  const float* emb     = (const float*)d_in[6];
  const float* enc_wx  = (const float*)d_in[7];
  const float* enc_bx  = (const float*)d_in[8];
  const float* enc_uh  = (const float*)d_in[9];
  const float* enc_bh  = (const float*)d_in[10];
  const float* comp_wx = (const float*)d_in[11];
  const float* comp_bx = (const float*)d_in[12];
  const float* comp_uh = (const float*)d_in[13];
  const float* comp_bh = (const float*)d_in[14];
  const float* proj_w  = (const float*)d_in[15];
  const float* proj_b  = (const float*)d_in[16];
  const float* cls_w1  = (const float*)d_in[17];
  const float* cls_b1  = (const float*)d_in[18];
  const float* cls_w2  = (const float*)d_in[19];
  const float* cls_b2  = (const float*)d_in[20];
  float* outp = (float*)d_out;

  // workspace layout (floats); ATT aliases CH (disjoint lifetimes)
  const size_t SZ_XG  = (size_t)2*B_*T_*HG;   // 9,830,400
  const size_t SZ_BTH = (size_t)2*B_*T_*H_;   // 2,457,600
  float* XG  = (float*)d_ws;
  float* EMB = XG  + SZ_XG;     // embeddings -> proj
  float* H1  = EMB + SZ_BTH;    // enc h -> comp h
  float* CH  = H1  + SZ_BTH;    // c history (scan-local); reused as ATT between scans
  float* FH  = CH  + SZ_BTH;    // fh = uh1 @ h
  float* UTE = FH  + SZ_BTH;    // uh1T enc (90000)
  float* UTC = UTE + (size_t)H_*H_;
  float* EW  = UTC + (size_t)H_*H_;          // 64*2048
  int*   EIDX = (int*)(EW + (size_t)64*ECAP);
  int*   CNT  = EIDX + (size_t)64*ECAP;
  int*   COFF = CNT  + 64*T_;
  int*   DEPTH= COFF + 64*T_;
  int*   HASP = DEPTH+ 64*T_;
  int*   MAXD = HASP + 64*T_;
  int*   LVLCNT = MAXD + 64;
  int*   WL   = LVLCNT + LMAX;               // LMAX*8192
  float* ATT  = CH;

  hipMemsetAsync(LVLCNT, 0, LMAX*sizeof(int), stream);
  // 1. embeddings + weight prep + graph analysis (independent)
  k_embed<<<2400, 256, 0, stream>>>(prem, hyp, emb, EMB);
  k_prep_uh1T<<<(H_*H_ + 255)/256, 256, 0, stream>>>(enc_uh, comp_uh, UTE, UTC);
  k_build<<<64, 256, 0, stream>>>(lg, rg, CNT, COFF, EIDX, EW, HASP, DEPTH, MAXD, LVLCNT, WL);
  // 2. enc xg = emb @ enc_wx^T + enc_bx
  k_gemm_nt<<<dim3(10, 64), 256, 0, stream>>>(EMB, enc_wx, enc_bx, XG, 2*B_*T_, HG, H_, 0);
  // 3. enc tree scan: one launch per level + serial tail
  for (int L = 0; L < LMAX; ++L)
    k_level<<<320, 1024, 0, stream>>>(XG, enc_bh, UTE, CNT, COFF, EIDX, EW, HASP, LVLCNT, WL, L, H1, CH, FH);
  k_tail<<<64, 320, 0, stream>>>(XG, enc_bh, UTE, CNT, COFF, EIDX, EW, HASP, DEPTH, MAXD, H1, CH, FH);
  // 4. attention both directions (CH dead -> ATT)
  k_attention<<<dim3(2, B_, T_/8), 256, 0, stream>>>(H1, plen, hlen, ATT);
  // 5. enhance -> XG (enc-xg dead)
  k_enhance<<<(unsigned)((SZ_XG)/256), 256, 0, stream>>>(H1, ATT, XG);
  // 6. proj = relu(enh @ proj_w^T + proj_b) -> EMB (embeddings dead)
  k_gemm_nt<<<dim3(3, 64), 256, 0, stream>>>(XG, proj_w, proj_b, EMB, 2*B_*T_, H_, HG, 1);
  // 7. comp xg = proj @ comp_wx^T + comp_bx -> XG (enh dead)
  k_gemm_nt<<<dim3(10, 64), 256, 0, stream>>>(EMB, comp_wx, comp_bx, XG, 2*B_*T_, HG, H_, 0);
  // 8. comp tree scan (ATT dead -> CH again)
  for (int L = 0; L < LMAX; ++L)
    k_level<<<320, 1024, 0, stream>>>(XG, comp_bh, UTC, CNT, COFF, EIDX, EW, HASP, LVLCNT, WL, L, H1, CH, FH);
  k_tail<<<64, 320, 0, stream>>>(XG, comp_bh, UTC, CNT, COFF, EIDX, EW, HASP, DEPTH, MAXD, H1, CH, FH);
  // 9. pool + classifier
  k_pool_classify<<<B_, 256, 0, stream>>>(H1, plen, hlen, cls_w1, cls_b1, cls_w2, cls_b2, outp);
}

// Round 4
// 1133.674 us; speedup vs baseline: 2.0275x; 1.0278x over previous
//
#include <hip/hip_runtime.h>
#include <math.h>

#define B_ 32
#define T_ 128
#define H_ 300
#define HG 1200   // 4*H
#define LMAX 10
#define WLCAP 8192
#define ECAP 2048
#define BKT 16

__device__ __forceinline__ float sigm(float x){ return 1.f/(1.f+expf(-x)); }

// ---------------- weight prep: uh[1] transpose ----------------
__global__ __launch_bounds__(256) void k_prep_uh1T(const float* __restrict__ enc_uh, const float* __restrict__ comp_uh,
    float* __restrict__ te, float* __restrict__ tc)
{
  int i = blockIdx.x*256 + threadIdx.x;
  if (i >= H_*H_) return;
  int m = i / H_, k = i % H_;
  te[i] = enc_uh[H_*H_ + (size_t)k*H_ + m];   // te[m][k] = uh1[k][m]
  tc[i] = comp_uh[H_*H_ + (size_t)k*H_ + m];
}

// ---------------- weight prep: folded proj weight (enhance fused away) ----------------
// enh = [e, a, e-a, e*a];  enh@W^T = e(W0+W2)^T + a(W1-W2)^T + (e*a)W3^T
// wp (300 x 900): [W0+W2 | W1-W2 | W3]
__global__ __launch_bounds__(256) void k_prep_projw(const float* __restrict__ pw, float* __restrict__ wp)
{
  int i = blockIdx.x*256 + threadIdx.x;
  if (i >= H_*900) return;
  int n = i / 900, k = i - n*900;
  const float* r = pw + (size_t)n*HG;
  float v;
  if (k < 300)      v = r[k] + r[600+k];
  else if (k < 600) v = r[k] - r[k+300];
  else              v = r[k+300];
  wp[i] = v;
}

// ---------------- graph analysis: edges, depths, level worklists (shared by both scans) ----------------
__global__ __launch_bounds__(256) void k_build(const float* __restrict__ lg, const float* __restrict__ rg,
    int* __restrict__ cnt_g, int* __restrict__ coff_g, int* __restrict__ eidx_g, float* __restrict__ ew_g,
    int* __restrict__ hasp_g, int* __restrict__ depth_g, int* __restrict__ maxd_g,
    int* __restrict__ lvlcnt_g, int* __restrict__ wl_g)
{
  int chain = blockIdx.x; int s = chain >> 5, b = chain & 31;
  const float* graph = (s ? rg : lg) + (size_t)b*T_*T_;
  int tid = threadIdx.x;
  __shared__ int cnt[T_], coff[T_], depth[T_], hasp[T_];
  __shared__ short eidx[ECAP];
  __shared__ float ew[ECAP];
  __shared__ int etot_s;
  if (tid < T_) hasp[tid] = 0;
  if (tid < T_) {
    int j = tid, c = 0;
    const float* gr = graph + (size_t)j*T_;
    for (int t = 0; t < j; ++t) c += (gr[t] != 0.f) ? 1 : 0;
    cnt[j] = c;
  }
  __syncthreads();
  if (tid == 0) { int a = 0; for (int j = 0; j < T_; ++j) { coff[j] = a; a += cnt[j]; } etot_s = a; }
  __syncthreads();
  if (tid < T_) {
    int j = tid, p = coff[j];
    const float* gr = graph + (size_t)j*T_;
    for (int t = 0; t < j; ++t) {
      float g = gr[t];
      if (g != 0.f && p < ECAP) { eidx[p] = (short)t; ew[p] = g; hasp[t] = 1; ++p; }
    }
  }
  __syncthreads();
  if (tid == 0) {
    int md = 0;
    for (int j = 0; j < T_; ++j) {
      int d = 0, e0 = coff[j], e1 = coff[j] + cnt[j];
      if (e1 > ECAP) e1 = ECAP;
      for (int k = e0; k < e1; ++k) { int dd = depth[eidx[k]] + 1; d = dd > d ? dd : d; }
      depth[j] = d; md = d > md ? d : md;
    }
    maxd_g[chain] = md;
  }
  __syncthreads();
  int base = chain * T_;
  if (tid < T_) {
    cnt_g[base+tid] = cnt[tid]; coff_g[base+tid] = coff[tid];
    hasp_g[base+tid] = hasp[tid]; depth_g[base+tid] = depth[tid];
    int L = depth[tid];
    if (L < LMAX) { int p = atomicAdd(&lvlcnt_g[L], 1); wl_g[L*WLCAP + p] = (chain << 8) | tid; }
  }
  int etot = etot_s; if (etot > ECAP) etot = ECAP;
  for (int i = tid; i < etot; i += 256) { eidx_g[chain*ECAP + i] = eidx[i]; ew_g[chain*ECAP + i] = ew[i]; }
}

// ---------------- per-level tree-LSTM: 4 nodes per block, all CUs ----------------
__global__ __launch_bounds__(1024) void k_level(
    const float* __restrict__ xg,   // (2,B,T,1200)
    const float* __restrict__ bhv,  // (4,300)
    const float* __restrict__ uh1T, // (300,300) [m][k] = uh1[k][m]
    const int* __restrict__ cnt_g, const int* __restrict__ coff_g,
    const int* __restrict__ eidx_g, const float* __restrict__ ew_g,
    const int* __restrict__ hasp_g, const int* __restrict__ lvlcnt_g, const int* __restrict__ wl_g,
    int L, float* __restrict__ hout, float* __restrict__ chist, float* __restrict__ fh)
{
  int count = lvlcnt_g[L];
  int nblk = (count + 3) >> 2;
  int tid = threadIdx.x;
  __shared__ float h_s[4][H_];
  __shared__ float psum[3][4][H_];
  __shared__ int nodes[4];
  __shared__ int anyp;
  for (int blk = blockIdx.x; blk < nblk; blk += gridDim.x) {
    int base = blk * 4;
    int nn = count - base; if (nn > 4) nn = 4;
    if (tid == 0) anyp = 0;
    __syncthreads();
    if (tid < 4) {
      int pk = (tid < nn) ? wl_g[L*WLCAP + base + tid] : -1;
      nodes[tid] = pk;
      if (pk >= 0 && hasp_g[(pk >> 8)*T_ + (pk & 255)]) atomicAdd(&anyp, 1);
    }
    __syncthreads();
    // gates + child accumulation
    for (int w = tid; w < nn*H_; w += 1024) {
      int n = w / H_, e = w - n*H_;
      int pk = nodes[n]; int chain = pk >> 8, j = pk & 255;
      size_t cb = (size_t)chain*T_*H_, xb = (size_t)chain*T_*HG;
      const float* xp = xg + xb + (size_t)j*HG;
      float x0 = xp[e], x1 = xp[H_+e], x2 = xp[2*H_+e], x3 = xp[3*H_+e];
      float iu  = sigm(x0 + bhv[e]) * tanhf(x3 + bhv[3*H_+e]);
      float og  = sigm(x2 + bhv[2*H_+e]);
      float x1b = x1 + bhv[H_+e];
      float acc = iu;
      int c0 = coff_g[chain*T_+j], c1 = c0 + cnt_g[chain*T_+j];
      const int* ei = eidx_g + chain*ECAP;
      const float* ewp = ew_g + chain*ECAP;
      for (int k = c0; k < c1; ++k) {
        int t = ei[k];
        acc += ewp[k] * sigm(x1b + fh[cb + (size_t)t*H_ + e]) * chist[cb + (size_t)t*H_ + e];
      }
      chist[cb + (size_t)j*H_ + e] = acc;
      float hv = og * tanhf(acc);
      hout[cb + (size_t)j*H_ + e] = hv;
      h_s[n][e] = hv;
    }
    __syncthreads();
    if (anyp > 0) {
      // fh = uh1 @ h, 4 nodes at once; thread (g,e): m in [g*100,g*100+100)
      if (tid < 3*H_) {
        int g = tid / H_, e = tid - g*H_;
        float a0=0.f, a1=0.f, a2=0.f, a3=0.f;
        const float* up = uh1T + e;
        int m0 = g*100, m1 = m0 + 100;
        #pragma unroll 4
        for (int m = m0; m < m1; ++m) {
          float u = up[(size_t)m*H_];
          a0 = fmaf(u, h_s[0][m], a0);
          a1 = fmaf(u, h_s[1][m], a1);
          a2 = fmaf(u, h_s[2][m], a2);
          a3 = fmaf(u, h_s[3][m], a3);
        }
        psum[g][0][e]=a0; psum[g][1][e]=a1; psum[g][2][e]=a2; psum[g][3][e]=a3;
      }
      __syncthreads();
      for (int w = tid; w < nn*H_; w += 1024) {
        int n = w / H_, e = w - n*H_;
        int pk = nodes[n]; int chain = pk >> 8, j = pk & 255;
        if (hasp_g[chain*T_+j]) {
          size_t cb = (size_t)chain*T_*H_;
          fh[cb + (size_t)j*H_ + e] = psum[0][n][e] + psum[1][n][e] + psum[2][n][e];
        }
      }
    }
    __syncthreads();
  }
}

// ---------------- serial tail for rare deep graphs (depth >= LMAX) ----------------
__global__ __launch_bounds__(320) void k_tail(const float* __restrict__ xg, const float* __restrict__ bhv,
    const float* __restrict__ uh1T, const int* __restrict__ cnt_g, const int* __restrict__ coff_g,
    const int* __restrict__ eidx_g, const float* __restrict__ ew_g, const int* __restrict__ hasp_g,
    const int* __restrict__ depth_g, const int* __restrict__ maxd_g,
    float* __restrict__ hout, float* __restrict__ chist, float* __restrict__ fh)
{
  int chain = blockIdx.x;
  if (maxd_g[chain] < LMAX) return;
  int tid = threadIdx.x;
  bool act = tid < H_;
  float bh0=0.f,bh1=0.f,bh2=0.f,bh3=0.f;
  if (act) { bh0=bhv[tid]; bh1=bhv[H_+tid]; bh2=bhv[2*H_+tid]; bh3=bhv[3*H_+tid]; }
  __shared__ float h_lds[H_];
  size_t cb = (size_t)chain*T_*H_, xb = (size_t)chain*T_*HG;
  const int* ei = eidx_g + chain*ECAP;
  const float* ewp = ew_g + chain*ECAP;
  for (int j = 0; j < T_; ++j) {
    if (depth_g[chain*T_+j] < LMAX) continue;
    if (act) {
      const float* xp = xg + xb + (size_t)j*HG;
      float x0 = xp[tid], x1 = xp[H_+tid], x2 = xp[2*H_+tid], x3 = xp[3*H_+tid];
      float acc = sigm(x0+bh0) * tanhf(x3+bh3);
      float og  = sigm(x2+bh2);
      float x1b = x1 + bh1;
      int c0 = coff_g[chain*T_+j], c1 = c0 + cnt_g[chain*T_+j];
      for (int k = c0; k < c1; ++k) {
        int t = ei[k];
        acc += ewp[k] * sigm(x1b + fh[cb + (size_t)t*H_ + tid]) * chist[cb + (size_t)t*H_ + tid];
      }
      chist[cb + (size_t)j*H_ + tid] = acc;
      float hv = og * tanhf(acc);
      hout[cb + (size_t)j*H_ + tid] = hv;
      h_lds[tid] = hv;
    }
    __syncthreads();
    if (hasp_g[chain*T_+j] && act) {
      float a = 0.f;
      const float* up = uh1T + tid;
      #pragma unroll 4
      for (int m = 0; m < H_; ++m) a = fmaf(up[(size_t)m*H_], h_lds[m], a);
      fh[cb + (size_t)j*H_ + tid] = a;
    }
    __syncthreads();
  }
}

// ---------------- fp32 GEMM, 128x128 tile, 512 threads, double-buffered LDS ----------------
// C[8192,N] = act(A[8192,K] @ W[N,K]^T + bias[N])
// mode 0: A plain (row stride K)
// mode 1: A = emb[tok[m]] gather (K=300)
// mode 2: A = [H1 | ATT | H1*ATT] segmented over K=900 (row stride 300 per segment)
__global__ __launch_bounds__(512) void k_gemm128(
    const float* __restrict__ A, const float* __restrict__ A2,
    const int* __restrict__ ptok, const int* __restrict__ htok, const float* __restrict__ embr,
    const float* __restrict__ W, const float* __restrict__ bias, float* __restrict__ C,
    int N, int K, int act, int mode)
{
  __shared__ float As[2][BKT][132];
  __shared__ float Ws[2][BKT][132];
  int bn = blockIdx.x * 128;
  int bm = blockIdx.y * 128;
  int tid = threadIdx.x;
  int lr = tid >> 2;        // staging row 0..127
  int kq = (tid & 3) * 4;   // staging k offset 0,4,8,12

  int arow = bm + lr;       // always < 8192
  const float* Ar1; const float* Ar2 = A2;
  if (mode == 1)      { int tok = (arow < 4096) ? ptok[arow] : htok[arow - 4096]; Ar1 = embr + (size_t)tok*H_; }
  else if (mode == 2) { Ar1 = A + (size_t)arow*H_; Ar2 = A2 + (size_t)arow*H_; }
  else                  Ar1 = A + (size_t)arow*K;
  int brow = bn + lr;
  const float* Wr = W + (size_t)brow*K;
  bool bok = brow < N;

  int NT = (K + BKT - 1) / BKT;
  float4 ra, rx, rb;
  int segv = 0;

  auto issue = [&](int t) {       // issue global loads for tile t
    int gk = t*BKT + kq;
    ra = make_float4(0.f,0.f,0.f,0.f); rb = make_float4(0.f,0.f,0.f,0.f); segv = 0;
    if (gk < K) {
      if (mode == 2) {
        int s = (gk >= 600) ? 2 : ((gk >= 300) ? 1 : 0);
        int kk = gk - s*300; segv = s;
        if (s == 0)      ra = *(const float4*)(Ar1 + kk);
        else if (s == 1) ra = *(const float4*)(Ar2 + kk);
        else { ra = *(const float4*)(Ar1 + kk); rx = *(const float4*)(Ar2 + kk); }
      } else ra = *(const float4*)(Ar1 + gk);
      if (bok) rb = *(const float4*)(Wr + gk);
    }
  };
  auto commit = [&](int buf) {    // write staged regs into LDS buffer
    float4 va = ra;
    if (mode == 2 && segv == 2) { va.x*=rx.x; va.y*=rx.y; va.z*=rx.z; va.w*=rx.w; }
    As[buf][kq+0][lr]=va.x; As[buf][kq+1][lr]=va.y; As[buf][kq+2][lr]=va.z; As[buf][kq+3][lr]=va.w;
    Ws[buf][kq+0][lr]=rb.x; Ws[buf][kq+1][lr]=rb.y; Ws[buf][kq+2][lr]=rb.z; Ws[buf][kq+3][lr]=rb.w;
  };

  float acc[4][8];
  #pragma unroll
  for (int i=0;i<4;++i)
    #pragma unroll
    for (int j=0;j<8;++j) acc[i][j]=0.f;

  int tx = tid & 15, ty = tid >> 4;   // tx: 8 cols, ty: 4 rows

  issue(0); commit(0);
  __syncthreads();
  int cur = 0;
  for (int t = 0; t < NT; ++t) {
    bool more = (t+1 < NT);
    if (more) issue(t+1);             // loads fly under the FMA block
    #pragma unroll
    for (int kk = 0; kk < BKT; ++kk) {
      float a[4], b[8];
      *(float4*)&a[0] = *(const float4*)&As[cur][kk][ty*4];
      *(float4*)&b[0] = *(const float4*)&Ws[cur][kk][tx*8];
      *(float4*)&b[4] = *(const float4*)&Ws[cur][kk][tx*8+4];
      #pragma unroll
      for (int i=0;i<4;++i)
        #pragma unroll
        for (int j=0;j<8;++j) acc[i][j] = fmaf(a[i], b[j], acc[i][j]);
    }
    if (more) commit(cur^1);          // writes other buffer; prev reads done at last barrier
    __syncthreads();                  // one barrier per K-step
    cur ^= 1;
  }
  #pragma unroll
  for (int i=0;i<4;++i) {
    int m = bm + ty*4 + i;
    float* cr = C + (size_t)m*N;
    #pragma unroll
    for (int j=0;j<8;++j) {
      int n = bn + tx*8 + j;
      if (n < N) {
        float v = acc[i][j] + bias[n];
        if (act) v = fmaxf(v, 0.f);
        cr[n] = v;
      }
    }
  }
}

// ---------------- fused attention (one direction per blockIdx.x) ----------------
#define NEGV -10000000.0f
__global__ __launch_bounds__(256) void k_attention(const float* __restrict__ H,  // (2,B,T,300)
    const int* __restrict__ plen, const int* __restrict__ hlen, float* __restrict__ ATT)
{
  int d = blockIdx.x;          // 0: q=enc_p,k=enc_h,mask=hlen ; 1: q=enc_h,k=enc_p,mask=plen
  int b = blockIdx.y;
  int r0 = blockIdx.z * 8;
  int qs = d, ks = 1 - d;
  int klen = (d == 0 ? hlen[b] : plen[b]);
  const float* Q  = H + ((size_t)(qs*B_ + b)*T_) * H_;
  const float* Kp = H + ((size_t)(ks*B_ + b)*T_) * H_;
  __shared__ float qr[8][H_];
  __shared__ float P[8][T_];
  __shared__ float rinv[8];
  int tid = threadIdx.x;

  for (int e = tid; e < 8*H_; e += 256) {
    int r = e / H_, m = e % H_;
    qr[r][m] = Q[(size_t)(r0 + r)*H_ + m];
  }
  __syncthreads();
  #pragma unroll
  for (int rep = 0; rep < 4; ++rep) {
    int e = tid + rep*256;
    int r = e >> 7, q = e & 127;
    float sc;
    if (q >= klen) sc = NEGV;
    else {
      sc = 0.f;
      const float* kp = Kp + (size_t)q*H_;
      #pragma unroll 4
      for (int m = 0; m < H_; ++m) sc = fmaf(qr[r][m], kp[m], sc);
    }
    P[r][q] = sc;
  }
  __syncthreads();
  {
    int g = tid >> 5, l = tid & 31;
    float s0 = P[g][l], s1 = P[g][l+32], s2 = P[g][l+64], s3 = P[g][l+96];
    float m0 = fmaxf(fmaxf(s0,s1), fmaxf(s2,s3));
    for (int o = 16; o > 0; o >>= 1) m0 = fmaxf(m0, __shfl_xor(m0, o, 32));
    float e0 = expf(s0-m0), e1 = expf(s1-m0), e2 = expf(s2-m0), e3 = expf(s3-m0);
    float sum = e0+e1+e2+e3;
    for (int o = 16; o > 0; o >>= 1) sum += __shfl_xor(sum, o, 32);
    P[g][l] = e0; P[g][l+32] = e1; P[g][l+64] = e2; P[g][l+96] = e3;
    if (l == 0) rinv[g] = 1.f / sum;
  }
  __syncthreads();
  float* out = ATT + ((size_t)(d*B_ + b)*T_ + r0) * H_;
  for (int e = tid; e < 8*H_; e += 256) {
    int r = e / H_, h = e % H_;
    float a = 0.f;
    const float* kp = Kp + h;
    #pragma unroll 4
    for (int q = 0; q < T_; ++q) a = fmaf(P[r][q], kp[(size_t)q*H_], a);
    out[(size_t)r*H_ + h] = a * rinv[r];
  }
}

// ---------------- pool + classifier ----------------
__global__ __launch_bounds__(256) void k_pool_classify(const float* __restrict__ H,  // comp h (2,B,T,300)
    const int* __restrict__ plen, const int* __restrict__ hlen,
    const float* __restrict__ w1, const float* __restrict__ b1,
    const float* __restrict__ w2, const float* __restrict__ b2,
    float* __restrict__ out)
{
  int b = blockIdx.x;
  __shared__ float v[HG];          // 1200
  __shared__ float hid[H_];
  int tid = threadIdx.x;
  for (int s = 0; s < 2; ++s) {
    int len = (s==0 ? plen[b] : hlen[b]);
    const float* hp = H + (size_t)(s*B_+b)*T_*H_;
    for (int k = tid; k < H_; k += 256) {
      float sum = 0.f, mx = NEGV;
      for (int t = 0; t < T_; ++t) {
        float x = hp[(size_t)t*H_ + k];
        if (t < len) { sum += x; mx = fmaxf(mx, x); }
      }
      v[s*600 + k]       = sum / (float)len;
      v[s*600 + 300 + k] = mx;
    }
  }
  __syncthreads();
  for (int k = tid; k < H_; k += 256) {
    float a = b1[k];
    const float* wr = w1 + (size_t)k*HG;
    #pragma unroll 4
    for (int m = 0; m < HG; ++m) a = fmaf(v[m], wr[m], a);
    hid[k] = tanhf(a);
  }
  __syncthreads();
  if (tid < 3) {
    float a = b2[tid];
    const float* wr = w2 + (size_t)tid*H_;
    for (int n = 0; n < H_; ++n) a = fmaf(hid[n], wr[n], a);
    out[b*3 + tid] = a;
  }
}

// ---------------- launch ----------------
extern "C" void kernel_launch(void* const* d_in, const int* in_sizes, int n_in,
                              void* d_out, int out_size, void* d_ws, size_t ws_size,
                              hipStream_t stream) {
  const int*   prem    = (const int*)d_in[0];
  const int*   plen    = (const int*)d_in[1];
  const int*   hyp     = (const int*)d_in[2];
  const int*   hlen    = (const int*)d_in[3];
  const float* lg      = (const float*)d_in[4];
  const float* rg      = (const float*)d_in[5];
  const float* emb     = (const float*)d_in[6];
  const float* enc_wx  = (const float*)d_in[7];
  const float* enc_bx  = (const float*)d_in[8];
  const float* enc_uh  = (const float*)d_in[9];
  const float* enc_bh  = (const float*)d_in[10];
  const float* comp_wx = (const float*)d_in[11];
  const float* comp_bx = (const float*)d_in[12];
  const float* comp_uh = (const float*)d_in[13];
  const float* comp_bh = (const float*)d_in[14];
  const float* proj_w  = (const float*)d_in[15];
  const float* proj_b  = (const float*)d_in[16];
  const float* cls_w1  = (const float*)d_in[17];
  const float* cls_b1  = (const float*)d_in[18];
  const float* cls_w2  = (const float*)d_in[19];
  const float* cls_b2  = (const float*)d_in[20];
  float* outp = (float*)d_out;

  // workspace layout (floats); ATT aliases CH (disjoint lifetimes)
  const size_t SZ_XG  = (size_t)2*B_*T_*HG;   // 9,830,400
  const size_t SZ_BTH = (size_t)2*B_*T_*H_;   // 2,457,600
  float* XG  = (float*)d_ws;    // enc-xg -> comp-xg
  float* PROJ= XG  + SZ_XG;     // proj output (8192x300)
  float* H1  = PROJ+ SZ_BTH;    // enc h -> comp h
  float* CH  = H1  + SZ_BTH;    // c history (scan-local); reused as ATT between scans
  float* FH  = CH  + SZ_BTH;    // fh = uh1 @ h
  float* UTE = FH  + SZ_BTH;    // uh1T enc (90000)
  float* UTC = UTE + (size_t)H_*H_;
  float* WP  = UTC + (size_t)H_*H_;          // folded proj weight (300x900)
  float* EW  = WP  + (size_t)H_*900;         // 64*2048
  int*   EIDX = (int*)(EW + (size_t)64*ECAP);
  int*   CNT  = EIDX + (size_t)64*ECAP;
  int*   COFF = CNT  + 64*T_;
  int*   DEPTH= COFF + 64*T_;
  int*   HASP = DEPTH+ 64*T_;
  int*   MAXD = HASP + 64*T_;
  int*   LVLCNT = MAXD + 64;
  int*   WL   = LVLCNT + LMAX;               // LMAX*8192
  float* ATT  = CH;

  hipMemsetAsync(LVLCNT, 0, LMAX*sizeof(int), stream);
  // 1. weight prep + graph analysis (independent)
  k_prep_uh1T<<<(H_*H_ + 255)/256, 256, 0, stream>>>(enc_uh, comp_uh, UTE, UTC);
  k_prep_projw<<<(H_*900 + 255)/256, 256, 0, stream>>>(proj_w, WP);
  k_build<<<64, 256, 0, stream>>>(lg, rg, CNT, COFF, EIDX, EW, HASP, DEPTH, MAXD, LVLCNT, WL);
  // 2. enc xg = emb-gather @ enc_wx^T + enc_bx (embedding fused into A-loader)
  k_gemm128<<<dim3(10, 64), 512, 0, stream>>>(nullptr, nullptr, prem, hyp, emb,
      enc_wx, enc_bx, XG, HG, H_, 0, 1);
  // 3. enc tree scan: one launch per level + serial tail
  for (int L = 0; L < LMAX; ++L)
    k_level<<<320, 1024, 0, stream>>>(XG, enc_bh, UTE, CNT, COFF, EIDX, EW, HASP, LVLCNT, WL, L, H1, CH, FH);
  k_tail<<<64, 320, 0, stream>>>(XG, enc_bh, UTE, CNT, COFF, EIDX, EW, HASP, DEPTH, MAXD, H1, CH, FH);
  // 4. attention both directions (CH dead -> ATT)
  k_attention<<<dim3(2, B_, T_/8), 256, 0, stream>>>(H1, plen, hlen, ATT);
  // 5. proj = relu([H1|ATT|H1*ATT] @ WP^T + proj_b)  (enhance fused into A-loader)
  k_gemm128<<<dim3(3, 64), 512, 0, stream>>>(H1, ATT, nullptr, nullptr, nullptr,
      WP, proj_b, PROJ, H_, 900, 1, 2);
  // 6. comp xg = proj @ comp_wx^T + comp_bx
  k_gemm128<<<dim3(10, 64), 512, 0, stream>>>(PROJ, nullptr, nullptr, nullptr, nullptr,
      comp_wx, comp_bx, XG, HG, H_, 0, 0);
  // 7. comp tree scan (ATT dead -> CH again)
  for (int L = 0; L < LMAX; ++L)
    k_level<<<320, 1024, 0, stream>>>(XG, comp_bh, UTC, CNT, COFF, EIDX, EW, HASP, LVLCNT, WL, L, H1, CH, FH);
  k_tail<<<64, 320, 0, stream>>>(XG, comp_bh, UTC, CNT, COFF, EIDX, EW, HASP, DEPTH, MAXD, H1, CH, FH);
  // 8. pool + classifier
  k_pool_classify<<<B_, 256, 0, stream>>>(H1, plen, hlen, cls_w1, cls_b1, cls_w2, cls_b2, outp);
}